// Round 1
// baseline (344.426 us; speedup 1.0000x reference)
//
#include <hip/hip_runtime.h>
#include <hip/hip_bf16.h>
#include <math.h>

// Problem constants (from reference): N=100000, K=10, T=7, D=7, O=32
#define T_ 7
#define D_ 7
#define K_ 10
#define O_ 32
#define NEG_SLOPE 0.01f

// het workspace layout: [T_+1][N][D_]  (t-major so K1 writes and K2 reads are
// wave-contiguous; slot t==T_ holds the self embedding).
// d_ws layout: [0..31] f32 output accumulator, pad to 64 floats, then het.

// ---------------- K0: zero the output accumulator --------------------------
__global__ void k0_zero(float* __restrict__ acc) {
    if (threadIdx.x < O_) acc[threadIdx.x] = 0.f;
}

// ---------------- K1: content einsum + masked mean, and self embedding -----
__global__ __launch_bounds__(256) void k1_content(
    const float* __restrict__ xhet,   // [T,N,K,D]
    const float* __restrict__ xnode,  // [N,D]
    const int*   __restrict__ types,  // [N]
    const float* __restrict__ Wc,     // [T,D,D]
    const float* __restrict__ bc,     // [T,D]
    float* __restrict__ het,          // [T+1][N][D]
    int N)
{
    const int n = blockIdx.x * 256 + threadIdx.x;
    const int t = blockIdx.y;   // 0..T_ ; wave-uniform
    if (n >= N) return;

    if (t < T_) {
        // W_content[t] is block-uniform -> scalar loads into SGPRs.
        float w[D_][D_], bias[D_];
        #pragma unroll
        for (int o = 0; o < D_; ++o) {
            bias[o] = bc[t * D_ + o];
            #pragma unroll
            for (int d = 0; d < D_; ++d) w[o][d] = Wc[(t * D_ + o) * D_ + d];
        }

        const float* xp = xhet + ((size_t)t * N + n) * (K_ * D_);  // 70 contiguous floats, 8B aligned
        float acc[D_] = {0.f, 0.f, 0.f, 0.f, 0.f, 0.f, 0.f};
        float cnt = 0.f;

        #pragma unroll
        for (int kk = 0; kk < K_ / 2; ++kk) {       // process k in pairs: 14 floats = 7 aligned float2
            const float2* p2 = (const float2*)(xp + kk * 14);
            float f[14];
            #pragma unroll
            for (int j = 0; j < 7; ++j) {
                float2 v = p2[j];
                f[2 * j]     = v.x;
                f[2 * j + 1] = v.y;
            }
            #pragma unroll
            for (int h = 0; h < 2; ++h) {
                float pre[D_];
                #pragma unroll
                for (int o = 0; o < D_; ++o) pre[o] = bias[o];
                #pragma unroll
                for (int d = 0; d < D_; ++d) {
                    const float xv = f[h * 7 + d];
                    #pragma unroll
                    for (int o = 0; o < D_; ++o) pre[o] = fmaf(xv, w[o][d], pre[o]);
                }
                // mask: row counted iff any emb element nonzero (lrelu preserves zeroness)
                bool nz = false;
                #pragma unroll
                for (int o = 0; o < D_; ++o) nz = nz || (pre[o] != 0.f);
                cnt += nz ? 1.f : 0.f;
                // zero rows contribute zero, so always accumulate lrelu(pre)
                #pragma unroll
                for (int o = 0; o < D_; ++o)
                    acc[o] += (pre[o] >= 0.f) ? pre[o] : NEG_SLOPE * pre[o];
            }
        }
        const float inv = 1.f / fmaxf(cnt, 1.f);
        float* hp = het + ((size_t)t * N + n) * D_;
        #pragma unroll
        for (int o = 0; o < D_; ++o) hp[o] = acc[o] * inv;
    } else {
        // self embedding with the node's own type-specific linear
        float x[D_];
        #pragma unroll
        for (int d = 0; d < D_; ++d) x[d] = xnode[(size_t)n * D_ + d];
        const int tp = types[n];
        const float* wp = Wc + (size_t)tp * D_ * D_;
        const float* bp = bc + (size_t)tp * D_;
        float* hp = het + ((size_t)T_ * N + n) * D_;
        #pragma unroll
        for (int o = 0; o < D_; ++o) {
            float pre = bp[o];
            #pragma unroll
            for (int d = 0; d < D_; ++d) pre = fmaf(x[d], wp[o * D_ + d], pre);
            hp[o] = (pre >= 0.f) ? pre : NEG_SLOPE * pre;
        }
    }
}

// ---------------- K2: final linear + sigmoid + mean-reduce -----------------
__global__ __launch_bounds__(256) void k2_final(
    const float* __restrict__ het,    // [T+1][N][D]
    const float* __restrict__ Wagg,   // [O, 56] row-major
    const float* __restrict__ bagg,   // [O]
    float* __restrict__ acc_out,      // [O] global accumulator
    int N)
{
    __shared__ float4 sW[O_ * 14];    // float4 view of [O][56]
    __shared__ float  sb[O_];
    __shared__ float  sacc[O_];

    const int tx = threadIdx.x;
    for (int i = tx; i < O_ * 14; i += 256) {
        const float* src = Wagg + i * 4;
        sW[i] = make_float4(src[0], src[1], src[2], src[3]);
    }
    if (tx < O_) { sb[tx] = bagg[tx]; sacc[tx] = 0.f; }
    __syncthreads();

    const int n = blockIdx.x * 256 + tx;
    const bool active = (n < N);

    float h[(T_ + 1) * D_];           // 56 floats
    if (active) {
        #pragma unroll
        for (int t = 0; t < T_ + 1; ++t) {
            const float* hp = het + ((size_t)t * N + n) * D_;
            #pragma unroll
            for (int o = 0; o < D_; ++o) h[t * D_ + o] = hp[o];
        }
    } else {
        #pragma unroll
        for (int j = 0; j < (T_ + 1) * D_; ++j) h[j] = 0.f;
    }

    const int lane = tx & 63;
    #pragma unroll 4
    for (int o = 0; o < O_; ++o) {
        float s = sb[o];
        #pragma unroll
        for (int q = 0; q < 14; ++q) {
            float4 wv = sW[o * 14 + q];
            s += h[4 * q]     * wv.x;
            s += h[4 * q + 1] * wv.y;
            s += h[4 * q + 2] * wv.z;
            s += h[4 * q + 3] * wv.w;
        }
        float val = active ? 1.f / (1.f + __expf(-s)) : 0.f;
        // wave64 reduce
        #pragma unroll
        for (int off = 32; off >= 1; off >>= 1) val += __shfl_down(val, off);
        if (lane == 0) atomicAdd(&sacc[o], val);
    }
    __syncthreads();
    if (tx < O_) atomicAdd(acc_out + tx, sacc[tx]);
}

// ---------------- K3: divide by N into d_out -------------------------------
__global__ void k3_finish(const float* __restrict__ acc, float* __restrict__ out, float invN) {
    if (threadIdx.x < O_) out[threadIdx.x] = acc[threadIdx.x] * invN;
}

extern "C" void kernel_launch(void* const* d_in, const int* in_sizes, int n_in,
                              void* d_out, int out_size, void* d_ws, size_t ws_size,
                              hipStream_t stream) {
    const float* xnode = (const float*)d_in[0];   // [N,D]
    const float* xhet  = (const float*)d_in[1];   // [T,N,K,D]
    const int*   types = (const int*)d_in[2];     // [N]
    const float* Wc    = (const float*)d_in[3];   // [T,D,D]
    const float* bc    = (const float*)d_in[4];   // [T,D]
    const float* Wagg  = (const float*)d_in[5];   // [O, 56]
    const float* bagg  = (const float*)d_in[6];   // [O]
    float* out = (float*)d_out;

    const int N = in_sizes[2];

    float* acc_out = (float*)d_ws;                // 32 floats (+pad to 64)
    float* het     = (float*)d_ws + 64;           // [T+1][N][D] = 5.6M floats

    const int nblk = (N + 255) / 256;

    k0_zero<<<1, 64, 0, stream>>>(acc_out);
    k1_content<<<dim3(nblk, T_ + 1), 256, 0, stream>>>(xhet, xnode, types, Wc, bc, het, N);
    k2_final<<<nblk, 256, 0, stream>>>(het, Wagg, bagg, acc_out, N);
    k3_finish<<<1, 64, 0, stream>>>(acc_out, out, 1.f / (float)N);
}